// Round 4
// baseline (1269.393 us; speedup 1.0000x reference)
//
#include <hip/hip_runtime.h>
#include <math.h>

#define NNODE 20000
#define NEDGE 320000

__device__ __forceinline__ float sspf(float x) {
    // softplus(x) - log(2), stable: max(x,0)+log1p(exp(-|x|)) - log2
    return fmaxf(x, 0.f) + log1pf(expf(-fabsf(x))) - 0.6931471805599453f;
}

// broadcast from lane l (ignores EXEC; convergent -> never sunk into branches)
__device__ __forceinline__ float rl(float v, int l) {
    return __int_as_float(__builtin_amdgcn_readlane(__float_as_int(v), l));
}

// ---------------- generic e3_linear: out = e3lin(in (+ add)) -----------------
// in/out layout: row = [s(64) | v(64x3 row-major)] = 256 floats
__global__ __launch_bounds__(256) void k_e3lin(
    const float* __restrict__ in, const float* __restrict__ add,
    float* __restrict__ out,
    const float* __restrict__ W0, const float* __restrict__ b0,
    const float* __restrict__ W1, int nrows)
{
    __shared__ float sW0[64 * 64];
    __shared__ float sW1[64 * 64];
    __shared__ float sb0[64];
    __shared__ float srow[4][256];
    const int tid = threadIdx.x;
    for (int i = tid; i < 64 * 16; i += 256) {
        ((float4*)sW0)[i] = ((const float4*)W0)[i];
        ((float4*)sW1)[i] = ((const float4*)W1)[i];
    }
    if (tid < 64) sb0[tid] = b0[tid];
    __syncthreads();

    const int rr = tid >> 6;
    const int v  = tid & 63;
    for (int r0 = blockIdx.x * 4; r0 < nrows; r0 += gridDim.x * 4) {
        // stage 4 input rows (optionally fused add), vectorized
        {
            int i = tid;                      // 256 float4 total, 256 threads
            int r = i >> 6, c = i & 63;
            int row = r0 + r;
            float4 val = make_float4(0.f, 0.f, 0.f, 0.f);
            if (row < nrows) {
                val = ((const float4*)(in + (size_t)row * 256))[c];
                if (add) {
                    float4 a = ((const float4*)(add + (size_t)row * 256))[c];
                    val.x += a.x; val.y += a.y; val.z += a.z; val.w += a.w;
                }
            }
            ((float4*)srow[r])[c] = val;
        }
        __syncthreads();

        int row = r0 + rr;
        if (row < nrows) {
            const float* rw = srow[rr];
            float s = 0.f, a0 = 0.f, a1 = 0.f, a2 = 0.f;
            #pragma unroll 16
            for (int u = 0; u < 64; ++u) {
                float w0 = sW0[u * 64 + v];
                float w1 = sW1[u * 64 + v];
                s  += rw[u] * w0;
                a0 += rw[64 + u * 3 + 0] * w1;
                a1 += rw[64 + u * 3 + 1] * w1;
                a2 += rw[64 + u * 3 + 2] * w1;
            }
            out[row * 256 + v]              = s  * 0.125f + sb0[v];
            out[row * 256 + 64 + v * 3 + 0] = a0 * 0.125f;
            out[row * 256 + 64 + v * 3 + 1] = a1 * 0.125f;
            out[row * 256 + 64 + v * 3 + 2] = a2 * 0.125f;
        }
        __syncthreads();
    }
}

// ---------------- gate: xg = [g_s | xv * g_v] ---------------------------------
__global__ __launch_bounds__(256) void k_gate(
    const float* __restrict__ x, float* __restrict__ xg,
    const float* __restrict__ Wg1, const float* __restrict__ bg1,
    const float* __restrict__ Wg2, const float* __restrict__ bg2,
    int nrows)
{
    __shared__ float sW1[128 * 128];
    __shared__ float sW2[128 * 128];
    __shared__ float sb1[128], sb2[128];
    __shared__ float srow[2][256];
    __shared__ float sf0[2][128];
    __shared__ float sh1[2][128];
    const int tid = threadIdx.x;
    for (int i = tid; i < 128 * 32; i += 256) {
        ((float4*)sW1)[i] = ((const float4*)Wg1)[i];
        ((float4*)sW2)[i] = ((const float4*)Wg2)[i];
    }
    if (tid < 128) { sb1[tid] = bg1[tid]; sb2[tid] = bg2[tid]; }
    __syncthreads();

    const int rr = tid >> 7;
    const int j  = tid & 127;
    for (int base = blockIdx.x * 2; base < nrows; base += gridDim.x * 2) {
        if (tid < 128) {
            int r = tid >> 6, c = tid & 63;
            int row = base + r;
            float4 v = make_float4(0.f, 0.f, 0.f, 0.f);
            if (row < nrows) v = ((const float4*)(x + (size_t)row * 256))[c];
            ((float4*)srow[r])[c] = v;
        }
        __syncthreads();
        // f0 = [xs | ||xv||]
        {
            float f;
            if (j < 64) f = srow[rr][j];
            else {
                int u = j - 64;
                float v0 = srow[rr][64 + u * 3 + 0];
                float v1 = srow[rr][64 + u * 3 + 1];
                float v2 = srow[rr][64 + u * 3 + 2];
                f = sqrtf(v0 * v0 + v1 * v1 + v2 * v2 + 1e-12f);
            }
            sf0[rr][j] = f;
        }
        __syncthreads();
        // h = silu(f0 @ Wg1 + bg1)
        {
            float acc = sb1[j];
            #pragma unroll 16
            for (int k = 0; k < 128; ++k) acc += sf0[rr][k] * sW1[k * 128 + j];
            sh1[rr][j] = acc / (1.f + expf(-acc));
        }
        __syncthreads();
        // g = h @ Wg2 + bg2 ; write xg
        {
            float acc = sb2[j];
            #pragma unroll 16
            for (int k = 0; k < 128; ++k) acc += sh1[rr][k] * sW2[k * 128 + j];
            int row = base + rr;
            if (row < nrows) {
                if (j < 64) xg[row * 256 + j] = acc;
                else {
                    int u = j - 64;
                    xg[row * 256 + 64 + u * 3 + 0] = srow[rr][64 + u * 3 + 0] * acc;
                    xg[row * 256 + 64 + u * 3 + 1] = srow[rr][64 + u * 3 + 1] * acc;
                    xg[row * 256 + 64 + u * 3 + 2] = srow[rr][64 + u * 3 + 2] * acc;
                }
            }
        }
        __syncthreads();
    }
}

// ---------------- fused edge kernel ------------------------------------------
// FULLY CONVERGENT main loop: no divergent branches anywhere. Lane-half
// specialization is folded into merged LDS weight tables + one cndmask:
//   sW1m[u*64+c]: c<32 -> Wf1[u][c]/8 ; c>=32 -> (Wl1[u][c-32]+Wl1[64+u][c-32])/sqrt(192)
//   sW1b[u*64+c]: c<32 -> 0           ; c>=32 -> Wl1[128+u][c-32]/sqrt(192)
// All readlane broadcasts execute at full EXEC (convergent ops cannot be sunk
// into branches -> their load producers execute for all 64 lanes).
#define EPW 4
__global__ __launch_bounds__(1024, 1) void k_edge(
    const float* __restrict__ pre, const float* __restrict__ slf,
    const int* __restrict__ ei, const float* __restrict__ eshp,
    const float* __restrict__ ea,
    const float* __restrict__ Wf1, const float* __restrict__ Wf2,
    const float* __restrict__ Wl1, const float* __restrict__ Wl2,
    float* __restrict__ acc)
{
    __shared__ float sW1m[64 * 64];
    __shared__ float sW1b[64 * 64];
    __shared__ float sWf2[32 * 320];   // * 1/sqrt(32)
    __shared__ float sWl2[32 * 320];   // * 1/sqrt(32)
    const int tid = threadIdx.x;
    const float sc_f1 = 0.125f;                 // 1/sqrt(64)
    const float sc_l1 = 0.07216878364870323f;   // 1/sqrt(192)
    const float sc_2  = 0.17677669529663687f;   // 1/sqrt(32)
    for (int i = tid; i < 64 * 64; i += 1024) {
        int u = i >> 6, c = i & 63, j = c & 31;
        if (c < 32) {
            sW1m[i] = Wf1[u * 32 + j] * sc_f1;
            sW1b[i] = 0.f;
        } else {
            sW1m[i] = (Wl1[u * 32 + j] + Wl1[(64 + u) * 32 + j]) * sc_l1;
            sW1b[i] = Wl1[(128 + u) * 32 + j] * sc_l1;
        }
    }
    for (int i = tid; i < 32 * 320; i += 1024) {
        sWf2[i] = Wf2[i] * sc_2;
        sWl2[i] = Wl2[i] * sc_2;
    }
    __syncthreads();

    const int lane  = tid & 63;
    const int wave  = tid >> 6;
    const int gwave = blockIdx.x * (blockDim.x >> 6) + wave;
    const int nwav  = gridDim.x * (blockDim.x >> 6);
    const bool lo   = (lane < 32);

    // NEDGE % EPW == 0 and all bases are multiples of EPW -> no tail guard needed
    for (int base = gwave * EPW; base < NEDGE; base += nwav * EPW) {
        int dstv[EPW], srcv[EPW];
        float psd[EPW], ip1[EPW], eav[EPW];
        #pragma unroll
        for (int t = 0; t < EPW; ++t) {
            int e = base + t;
            int d = ei[e], s = ei[NEDGE + e];
            dstv[t] = d; srcv[t] = s;
            psd[t] = pre[d * 256 + lane];
            float pd0 = pre[d * 256 + 64 + lane * 3 + 0];
            float pd1 = pre[d * 256 + 64 + lane * 3 + 1];
            float pd2 = pre[d * 256 + 64 + lane * 3 + 2];
            float ps0 = pre[s * 256 + 64 + lane * 3 + 0];
            float ps1 = pre[s * 256 + 64 + lane * 3 + 1];
            float ps2 = pre[s * 256 + 64 + lane * 3 + 2];
            ip1[t] = (pd0 * ps0 + pd1 * ps1 + pd2 * ps2) * (1.f / 3.f);
            eav[t] = ea[e * 64 + lane];
        }

        // h-phase (convergent): lanes 0..31 build hA (edge_attr net),
        // lanes 32..63 build hB (s0 net), via merged weights + cndmask.
        float hacc[EPW] = {0.f, 0.f, 0.f, 0.f};
        #pragma unroll 16
        for (int uu = 0; uu < 64; ++uu) {
            float wm = sW1m[uu * 64 + lane];
            float wb = sW1b[uu * 64 + lane];
            #pragma unroll
            for (int t = 0; t < EPW; ++t) {
                float bA = rl(eav[t], uu);
                float bP = rl(psd[t], uu);
                float bI = rl(ip1[t], uu);
                float b1 = lo ? bA : bP;
                hacc[t] += b1 * wm + bI * wb;
            }
        }
        float hval[EPW];
        #pragma unroll
        for (int t = 0; t < EPW; ++t) hval[t] = sspf(hacc[t]);

        // combine: w[k][u] = (hA . Wf2[:,k*64+u]) * (hB . Wl2[:,k*64+u])
        float aA[EPW][5], aB[EPW][5];
        #pragma unroll
        for (int t = 0; t < EPW; ++t)
            #pragma unroll
            for (int k = 0; k < 5; ++k) { aA[t][k] = 0.f; aB[t][k] = 0.f; }
        #pragma unroll 8
        for (int jj = 0; jj < 32; ++jj) {
            float wfa[5], wlb[5];
            #pragma unroll
            for (int k = 0; k < 5; ++k) {
                wfa[k] = sWf2[jj * 320 + k * 64 + lane];
                wlb[k] = sWl2[jj * 320 + k * 64 + lane];
            }
            #pragma unroll
            for (int t = 0; t < EPW; ++t) {
                float hA = rl(hval[t], jj);
                float hB = rl(hval[t], jj + 32);
                #pragma unroll
                for (int k = 0; k < 5; ++k) {
                    aA[t][k] += hA * wfa[k];
                    aB[t][k] += hB * wlb[k];
                }
            }
        }

        // output + scatter
        #pragma unroll
        for (int t = 0; t < EPW; ++t) {
            int e = base + t;
            float w0 = aA[t][0] * aB[t][0];
            float w1 = aA[t][1] * aB[t][1];
            float w2 = aA[t][2] * aB[t][2];
            float w3 = aA[t][3] * aB[t][3];
            float w4 = aA[t][4] * aB[t][4];
            int s = srcv[t];
            float es  = slf[s * 256 + lane];
            float ev0 = slf[s * 256 + 64 + lane * 3 + 0];
            float ev1 = slf[s * 256 + 64 + lane * 3 + 1];
            float ev2 = slf[s * 256 + 64 + lane * 3 + 2];
            float s0v = eshp[e * 4 + 0];
            float sx  = eshp[e * 4 + 1];
            float sy  = eshp[e * 4 + 2];
            float sz  = eshp[e * 4 + 3];
            float dotv = ev0 * sx + ev1 * sy + ev2 * sz;
            const float PW_S = 0.4472135954999579f;   // sqrt(1/5)
            const float PW_V = 0.7745966692414834f;   // sqrt(3/5)
            const float IS3  = 0.5773502691896258f;   // 1/sqrt(3)
            const float IS2  = 0.7071067811865476f;   // 1/sqrt(2)
            float outs = PW_S * (w0 * es * s0v + w3 * dotv * IS3);
            float cx = ev1 * sz - ev2 * sy;
            float cy = ev2 * sx - ev0 * sz;
            float cz = ev0 * sy - ev1 * sx;
            float ov0 = PW_V * (w1 * es * sx + w2 * ev0 * s0v + w4 * cx * IS2);
            float ov1 = PW_V * (w1 * es * sy + w2 * ev1 * s0v + w4 * cy * IS2);
            float ov2 = PW_V * (w1 * es * sz + w2 * ev2 * s0v + w4 * cz * IS2);
            int d = dstv[t];
            atomicAdd(&acc[d * 256 + lane], outs);
            atomicAdd(&acc[d * 256 + 64 + lane * 3 + 0], ov0);
            atomicAdd(&acc[d * 256 + 64 + lane * 3 + 1], ov1);
            atomicAdd(&acc[d * 256 + 64 + lane * 3 + 2], ov2);
        }
    }
}

extern "C" void kernel_launch(void* const* d_in, const int* in_sizes, int n_in,
                              void* d_out, int out_size, void* d_ws, size_t ws_size,
                              hipStream_t stream) {
    const float* x     = (const float*)d_in[0];
    const int*   ei    = (const int*)  d_in[1];
    const float* esh   = (const float*)d_in[2];
    const float* eattr = (const float*)d_in[3];
    const float* Wpre0 = (const float*)d_in[4];
    const float* bpre0 = (const float*)d_in[5];
    const float* Wpre1 = (const float*)d_in[6];
    const float* Wg1   = (const float*)d_in[7];
    const float* bg1   = (const float*)d_in[8];
    const float* Wg2   = (const float*)d_in[9];
    const float* bg2   = (const float*)d_in[10];
    const float* Wn0   = (const float*)d_in[11];
    const float* bn0   = (const float*)d_in[12];
    const float* Wn1   = (const float*)d_in[13];
    const float* Wf1   = (const float*)d_in[14];
    const float* Wf2   = (const float*)d_in[15];
    const float* Wl1   = (const float*)d_in[16];
    const float* Wl2   = (const float*)d_in[17];
    const float* Wo0   = (const float*)d_in[18];
    const float* bo0   = (const float*)d_in[19];
    const float* Wo1   = (const float*)d_in[20];
    float* out = (float*)d_out;
    float* ws  = (float*)d_ws;

    float* pre = ws;                               // N*256
    float* xg  = ws + (size_t)NNODE * 256;         // N*256
    float* slf = ws + (size_t)NNODE * 256 * 2;     // N*256
    float* acc = ws + (size_t)NNODE * 256 * 3;     // N*256

    hipMemsetAsync(acc, 0, (size_t)NNODE * 256 * sizeof(float), stream);
    k_e3lin<<<1280, 256, 0, stream>>>(x,  nullptr, pre, Wpre0, bpre0, Wpre1, NNODE);
    k_gate <<<512,  256, 0, stream>>>(x,  xg, Wg1, bg1, Wg2, bg2, NNODE);
    k_e3lin<<<1280, 256, 0, stream>>>(xg, nullptr, slf, Wn0, bn0, Wn1, NNODE);
    k_edge <<<256, 1024, 0, stream>>>(pre, slf, ei, esh, eattr, Wf1, Wf2, Wl1, Wl2, acc);
    k_e3lin<<<1280, 256, 0, stream>>>(acc, slf, out, Wo0, bo0, Wo1, NNODE);
}

// Round 5
// 1203.632 us; speedup vs baseline: 1.0546x; 1.0546x over previous
//
#include <hip/hip_runtime.h>
#include <math.h>

#define NNODE 20000
#define NEDGE 320000

__device__ __forceinline__ float sspf(float x) {
    // softplus(x) - log(2), stable: max(x,0)+log1p(exp(-|x|)) - log2
    return fmaxf(x, 0.f) + log1pf(expf(-fabsf(x))) - 0.6931471805599453f;
}

// ---------------- generic e3_linear: out = e3lin(in (+ add)) -----------------
// in/out layout: row = [s(64) | v(64x3 row-major)] = 256 floats
__global__ __launch_bounds__(256) void k_e3lin(
    const float* __restrict__ in, const float* __restrict__ add,
    float* __restrict__ out,
    const float* __restrict__ W0, const float* __restrict__ b0,
    const float* __restrict__ W1, int nrows)
{
    __shared__ float sW0[64 * 64];
    __shared__ float sW1[64 * 64];
    __shared__ float sb0[64];
    __shared__ float srow[4][256];
    const int tid = threadIdx.x;
    for (int i = tid; i < 64 * 16; i += 256) {
        ((float4*)sW0)[i] = ((const float4*)W0)[i];
        ((float4*)sW1)[i] = ((const float4*)W1)[i];
    }
    if (tid < 64) sb0[tid] = b0[tid];
    __syncthreads();

    const int rr = tid >> 6;
    const int v  = tid & 63;
    for (int r0 = blockIdx.x * 4; r0 < nrows; r0 += gridDim.x * 4) {
        // stage 4 input rows (optionally fused add), vectorized
        {
            int i = tid;                      // 256 float4 total, 256 threads
            int r = i >> 6, c = i & 63;
            int row = r0 + r;
            float4 val = make_float4(0.f, 0.f, 0.f, 0.f);
            if (row < nrows) {
                val = ((const float4*)(in + (size_t)row * 256))[c];
                if (add) {
                    float4 a = ((const float4*)(add + (size_t)row * 256))[c];
                    val.x += a.x; val.y += a.y; val.z += a.z; val.w += a.w;
                }
            }
            ((float4*)srow[r])[c] = val;
        }
        __syncthreads();

        int row = r0 + rr;
        if (row < nrows) {
            const float* rw = srow[rr];
            float s = 0.f, a0 = 0.f, a1 = 0.f, a2 = 0.f;
            #pragma unroll 16
            for (int u = 0; u < 64; ++u) {
                float w0 = sW0[u * 64 + v];
                float w1 = sW1[u * 64 + v];
                s  += rw[u] * w0;
                a0 += rw[64 + u * 3 + 0] * w1;
                a1 += rw[64 + u * 3 + 1] * w1;
                a2 += rw[64 + u * 3 + 2] * w1;
            }
            out[row * 256 + v]              = s  * 0.125f + sb0[v];
            out[row * 256 + 64 + v * 3 + 0] = a0 * 0.125f;
            out[row * 256 + 64 + v * 3 + 1] = a1 * 0.125f;
            out[row * 256 + 64 + v * 3 + 2] = a2 * 0.125f;
        }
        __syncthreads();
    }
}

// ---------------- gate: xg = [g_s | xv * g_v] ---------------------------------
__global__ __launch_bounds__(256) void k_gate(
    const float* __restrict__ x, float* __restrict__ xg,
    const float* __restrict__ Wg1, const float* __restrict__ bg1,
    const float* __restrict__ Wg2, const float* __restrict__ bg2,
    int nrows)
{
    __shared__ float sW1[128 * 128];
    __shared__ float sW2[128 * 128];
    __shared__ float sb1[128], sb2[128];
    __shared__ float srow[2][256];
    __shared__ float sf0[2][128];
    __shared__ float sh1[2][128];
    const int tid = threadIdx.x;
    for (int i = tid; i < 128 * 32; i += 256) {
        ((float4*)sW1)[i] = ((const float4*)Wg1)[i];
        ((float4*)sW2)[i] = ((const float4*)Wg2)[i];
    }
    if (tid < 128) { sb1[tid] = bg1[tid]; sb2[tid] = bg2[tid]; }
    __syncthreads();

    const int rr = tid >> 7;
    const int j  = tid & 127;
    for (int base = blockIdx.x * 2; base < nrows; base += gridDim.x * 2) {
        if (tid < 128) {
            int r = tid >> 6, c = tid & 63;
            int row = base + r;
            float4 v = make_float4(0.f, 0.f, 0.f, 0.f);
            if (row < nrows) v = ((const float4*)(x + (size_t)row * 256))[c];
            ((float4*)srow[r])[c] = v;
        }
        __syncthreads();
        // f0 = [xs | ||xv||]
        {
            float f;
            if (j < 64) f = srow[rr][j];
            else {
                int u = j - 64;
                float v0 = srow[rr][64 + u * 3 + 0];
                float v1 = srow[rr][64 + u * 3 + 1];
                float v2 = srow[rr][64 + u * 3 + 2];
                f = sqrtf(v0 * v0 + v1 * v1 + v2 * v2 + 1e-12f);
            }
            sf0[rr][j] = f;
        }
        __syncthreads();
        // h = silu(f0 @ Wg1 + bg1)
        {
            float acc = sb1[j];
            #pragma unroll 16
            for (int k = 0; k < 128; ++k) acc += sf0[rr][k] * sW1[k * 128 + j];
            sh1[rr][j] = acc / (1.f + expf(-acc));
        }
        __syncthreads();
        // g = h @ Wg2 + bg2 ; write xg
        {
            float acc = sb2[j];
            #pragma unroll 16
            for (int k = 0; k < 128; ++k) acc += sh1[rr][k] * sW2[k * 128 + j];
            int row = base + rr;
            if (row < nrows) {
                if (j < 64) xg[row * 256 + j] = acc;
                else {
                    int u = j - 64;
                    xg[row * 256 + 64 + u * 3 + 0] = srow[rr][64 + u * 3 + 0] * acc;
                    xg[row * 256 + 64 + u * 3 + 1] = srow[rr][64 + u * 3 + 1] * acc;
                    xg[row * 256 + 64 + u * 3 + 2] = srow[rr][64 + u * 3 + 2] * acc;
                }
            }
        }
        __syncthreads();
    }
}

// ---------------- fused edge kernel ------------------------------------------
// EPW=2, no readlane: each wave stages its 2 edges' inputs (eav|psd|ip1) and
// h-vector into PRIVATE per-wave LDS slices; reads are broadcast / 2-way
// (free). Same-wave producer->consumer => no barriers in the main loop.
// Lane-half specialization folded into the read address (+0 / +64) and the
// merged weight table sW1mb ({wm, wb} float2):
//   col<32: wm=Wf1[u][col]/8,                       wb=0
//   col>=32: wm=(Wl1[u][c]+Wl1[64+u][c])/sqrt(192), wb=Wl1[128+u][c]/sqrt(192)
#define EPW 2
__global__ __launch_bounds__(1024, 4) void k_edge(
    const float* __restrict__ pre, const float* __restrict__ slf,
    const int* __restrict__ ei, const float* __restrict__ eshp,
    const float* __restrict__ ea,
    const float* __restrict__ Wf1, const float* __restrict__ Wf2,
    const float* __restrict__ Wl1, const float* __restrict__ Wl2,
    float* __restrict__ acc)
{
    __shared__ float2 sW1mb[64 * 64];     // 32KB  {wm, wb}
    __shared__ float4 sW2a[32 * 64];      // 32KB  wfa[0..3]
    __shared__ float4 sW2b[32 * 64];      // 32KB  wlb[0..3]
    __shared__ float2 sW2c[32 * 64];      // 16KB  {wfa[4], wlb[4]}
    __shared__ float  sIN[16][EPW][192];  // 24KB  per-wave input staging
    __shared__ float  sH [16][EPW][64];   // 8KB   per-wave h staging
    const int tid = threadIdx.x;
    const float sc_f1 = 0.125f;                 // 1/sqrt(64)
    const float sc_l1 = 0.07216878364870323f;   // 1/sqrt(192)
    const float sc_2  = 0.17677669529663687f;   // 1/sqrt(32)
    for (int i = tid; i < 64 * 64; i += 1024) {
        int u = i >> 6, c = i & 63, j = c & 31;
        float wm, wb;
        if (c < 32) {
            wm = Wf1[u * 32 + j] * sc_f1;
            wb = 0.f;
        } else {
            wm = (Wl1[u * 32 + j] + Wl1[(64 + u) * 32 + j]) * sc_l1;
            wb = Wl1[(128 + u) * 32 + j] * sc_l1;
        }
        sW1mb[i] = make_float2(wm, wb);
    }
    for (int i = tid; i < 32 * 64; i += 1024) {
        int jj = i >> 6, col = i & 63;
        const float* f2 = Wf2 + jj * 320 + col;
        const float* l2 = Wl2 + jj * 320 + col;
        sW2a[i] = make_float4(f2[0] * sc_2, f2[64] * sc_2, f2[128] * sc_2, f2[192] * sc_2);
        sW2b[i] = make_float4(l2[0] * sc_2, l2[64] * sc_2, l2[128] * sc_2, l2[192] * sc_2);
        sW2c[i] = make_float2(f2[256] * sc_2, l2[256] * sc_2);
    }
    __syncthreads();

    const int lane  = tid & 63;
    const int w     = tid >> 6;
    const int gwave = blockIdx.x * (blockDim.x >> 6) + w;
    const int nwav  = gridDim.x * (blockDim.x >> 6);
    // per-lane base into this wave's staging slice; +64 selects psd for hi half
    const float* inb = &sIN[w][0][(lane >> 5) << 6];

    for (int base0 = gwave * EPW; base0 < NEDGE; base0 += nwav * EPW) {
        const int base = __builtin_amdgcn_readfirstlane(base0);  // wave-uniform -> scalar loads
        int dstv[EPW], srcv[EPW];
        #pragma unroll
        for (int t = 0; t < EPW; ++t) {
            int e = base + t;
            int d = ei[e], s = ei[NEDGE + e];
            dstv[t] = d; srcv[t] = s;
            float psd = pre[d * 256 + lane];
            float pd0 = pre[d * 256 + 64 + lane * 3 + 0];
            float pd1 = pre[d * 256 + 64 + lane * 3 + 1];
            float pd2 = pre[d * 256 + 64 + lane * 3 + 2];
            float ps0 = pre[s * 256 + 64 + lane * 3 + 0];
            float ps1 = pre[s * 256 + 64 + lane * 3 + 1];
            float ps2 = pre[s * 256 + 64 + lane * 3 + 2];
            float ip1 = (pd0 * ps0 + pd1 * ps1 + pd2 * ps2) * (1.f / 3.f);
            float eav = ea[e * 64 + lane];
            sIN[w][t][lane]       = eav;
            sIN[w][t][64 + lane]  = psd;
            sIN[w][t][128 + lane] = ip1;
        }
        // no barrier: same wave wrote, same wave reads (lgkmcnt ordering)

        // h-phase: lane j<32 -> hA_j (edge_attr net), lane 32+j -> hB_j (s0 net)
        float hacc[EPW] = {0.f, 0.f};
        #pragma unroll 16
        for (int uu = 0; uu < 64; ++uu) {
            float2 wmb = sW1mb[uu * 64 + lane];
            #pragma unroll
            for (int t = 0; t < EPW; ++t) {
                float b1 = inb[t * 192 + uu];          // eav (lo) / psd (hi)
                float bI = sIN[w][t][128 + uu];        // ip1 broadcast
                hacc[t] += b1 * wmb.x + bI * wmb.y;
            }
        }
        #pragma unroll
        for (int t = 0; t < EPW; ++t) sH[w][t][lane] = sspf(hacc[t]);

        // combine: aA[k][col] = hA . Wf2[:,k*64+col], aB likewise; w = aA*aB
        float aA[EPW][5], aB[EPW][5];
        #pragma unroll
        for (int t = 0; t < EPW; ++t)
            #pragma unroll
            for (int k = 0; k < 5; ++k) { aA[t][k] = 0.f; aB[t][k] = 0.f; }
        #pragma unroll 8
        for (int jj = 0; jj < 32; ++jj) {
            float4 wa = sW2a[jj * 64 + lane];
            float4 wb = sW2b[jj * 64 + lane];
            float2 wc = sW2c[jj * 64 + lane];
            #pragma unroll
            for (int t = 0; t < EPW; ++t) {
                float hA = sH[w][t][jj];        // broadcast
                float hB = sH[w][t][32 + jj];   // broadcast
                aA[t][0] += hA * wa.x; aA[t][1] += hA * wa.y;
                aA[t][2] += hA * wa.z; aA[t][3] += hA * wa.w;
                aA[t][4] += hA * wc.x;
                aB[t][0] += hB * wb.x; aB[t][1] += hB * wb.y;
                aB[t][2] += hB * wb.z; aB[t][3] += hB * wb.w;
                aB[t][4] += hB * wc.y;
            }
        }

        // output + scatter
        #pragma unroll
        for (int t = 0; t < EPW; ++t) {
            int e = base + t;
            float w0 = aA[t][0] * aB[t][0];
            float w1 = aA[t][1] * aB[t][1];
            float w2 = aA[t][2] * aB[t][2];
            float w3 = aA[t][3] * aB[t][3];
            float w4 = aA[t][4] * aB[t][4];
            int s = srcv[t];
            float es  = slf[s * 256 + lane];
            float ev0 = slf[s * 256 + 64 + lane * 3 + 0];
            float ev1 = slf[s * 256 + 64 + lane * 3 + 1];
            float ev2 = slf[s * 256 + 64 + lane * 3 + 2];
            float s0v = eshp[e * 4 + 0];
            float sx  = eshp[e * 4 + 1];
            float sy  = eshp[e * 4 + 2];
            float sz  = eshp[e * 4 + 3];
            float dotv = ev0 * sx + ev1 * sy + ev2 * sz;
            const float PW_S = 0.4472135954999579f;   // sqrt(1/5)
            const float PW_V = 0.7745966692414834f;   // sqrt(3/5)
            const float IS3  = 0.5773502691896258f;   // 1/sqrt(3)
            const float IS2  = 0.7071067811865476f;   // 1/sqrt(2)
            float outs = PW_S * (w0 * es * s0v + w3 * dotv * IS3);
            float cx = ev1 * sz - ev2 * sy;
            float cy = ev2 * sx - ev0 * sz;
            float cz = ev0 * sy - ev1 * sx;
            float ov0 = PW_V * (w1 * es * sx + w2 * ev0 * s0v + w4 * cx * IS2);
            float ov1 = PW_V * (w1 * es * sy + w2 * ev1 * s0v + w4 * cy * IS2);
            float ov2 = PW_V * (w1 * es * sz + w2 * ev2 * s0v + w4 * cz * IS2);
            int d = dstv[t];
            atomicAdd(&acc[d * 256 + lane], outs);
            atomicAdd(&acc[d * 256 + 64 + lane * 3 + 0], ov0);
            atomicAdd(&acc[d * 256 + 64 + lane * 3 + 1], ov1);
            atomicAdd(&acc[d * 256 + 64 + lane * 3 + 2], ov2);
        }
    }
}

extern "C" void kernel_launch(void* const* d_in, const int* in_sizes, int n_in,
                              void* d_out, int out_size, void* d_ws, size_t ws_size,
                              hipStream_t stream) {
    const float* x     = (const float*)d_in[0];
    const int*   ei    = (const int*)  d_in[1];
    const float* esh   = (const float*)d_in[2];
    const float* eattr = (const float*)d_in[3];
    const float* Wpre0 = (const float*)d_in[4];
    const float* bpre0 = (const float*)d_in[5];
    const float* Wpre1 = (const float*)d_in[6];
    const float* Wg1   = (const float*)d_in[7];
    const float* bg1   = (const float*)d_in[8];
    const float* Wg2   = (const float*)d_in[9];
    const float* bg2   = (const float*)d_in[10];
    const float* Wn0   = (const float*)d_in[11];
    const float* bn0   = (const float*)d_in[12];
    const float* Wn1   = (const float*)d_in[13];
    const float* Wf1   = (const float*)d_in[14];
    const float* Wf2   = (const float*)d_in[15];
    const float* Wl1   = (const float*)d_in[16];
    const float* Wl2   = (const float*)d_in[17];
    const float* Wo0   = (const float*)d_in[18];
    const float* bo0   = (const float*)d_in[19];
    const float* Wo1   = (const float*)d_in[20];
    float* out = (float*)d_out;
    float* ws  = (float*)d_ws;

    float* pre = ws;                               // N*256
    float* xg  = ws + (size_t)NNODE * 256;         // N*256
    float* slf = ws + (size_t)NNODE * 256 * 2;     // N*256
    float* acc = ws + (size_t)NNODE * 256 * 3;     // N*256

    hipMemsetAsync(acc, 0, (size_t)NNODE * 256 * sizeof(float), stream);
    k_e3lin<<<1280, 256, 0, stream>>>(x,  nullptr, pre, Wpre0, bpre0, Wpre1, NNODE);
    k_gate <<<512,  256, 0, stream>>>(x,  xg, Wg1, bg1, Wg2, bg2, NNODE);
    k_e3lin<<<1280, 256, 0, stream>>>(xg, nullptr, slf, Wn0, bn0, Wn1, NNODE);
    k_edge <<<256, 1024, 0, stream>>>(pre, slf, ei, esh, eattr, Wf1, Wf2, Wl1, Wl2, acc);
    k_e3lin<<<1280, 256, 0, stream>>>(acc, slf, out, Wo0, bo0, Wo1, NNODE);
}

// Round 8
// 1136.071 us; speedup vs baseline: 1.1174x; 1.0595x over previous
//
#include <hip/hip_runtime.h>
#include <math.h>

#define NNODE 20000
#define NEDGE 320000

__device__ __forceinline__ float sspf(float x) {
    // softplus(x) - log(2), stable: max(x,0)+log1p(exp(-|x|)) - log2
    return fmaxf(x, 0.f) + log1pf(expf(-fabsf(x))) - 0.6931471805599453f;
}

// ---------------- generic e3_linear: out = e3lin(in (+ add)) -----------------
// in/out layout: row = [s(64) | v(64x3 row-major)] = 256 floats
__global__ __launch_bounds__(256) void k_e3lin(
    const float* __restrict__ in, const float* __restrict__ add,
    float* __restrict__ out,
    const float* __restrict__ W0, const float* __restrict__ b0,
    const float* __restrict__ W1, int nrows)
{
    __shared__ float sW0[64 * 64];
    __shared__ float sW1[64 * 64];
    __shared__ float sb0[64];
    __shared__ float srow[4][256];
    const int tid = threadIdx.x;
    for (int i = tid; i < 64 * 16; i += 256) {
        ((float4*)sW0)[i] = ((const float4*)W0)[i];
        ((float4*)sW1)[i] = ((const float4*)W1)[i];
    }
    if (tid < 64) sb0[tid] = b0[tid];
    __syncthreads();

    const int rr = tid >> 6;
    const int v  = tid & 63;
    for (int r0 = blockIdx.x * 4; r0 < nrows; r0 += gridDim.x * 4) {
        {
            int i = tid;                      // 256 float4 total, 256 threads
            int r = i >> 6, c = i & 63;
            int row = r0 + r;
            float4 val = make_float4(0.f, 0.f, 0.f, 0.f);
            if (row < nrows) {
                val = ((const float4*)(in + (size_t)row * 256))[c];
                if (add) {
                    float4 a = ((const float4*)(add + (size_t)row * 256))[c];
                    val.x += a.x; val.y += a.y; val.z += a.z; val.w += a.w;
                }
            }
            ((float4*)srow[r])[c] = val;
        }
        __syncthreads();

        int row = r0 + rr;
        if (row < nrows) {
            const float* rw = srow[rr];
            float s = 0.f, a0 = 0.f, a1 = 0.f, a2 = 0.f;
            #pragma unroll 16
            for (int u = 0; u < 64; ++u) {
                float w0 = sW0[u * 64 + v];
                float w1 = sW1[u * 64 + v];
                s  += rw[u] * w0;
                a0 += rw[64 + u * 3 + 0] * w1;
                a1 += rw[64 + u * 3 + 1] * w1;
                a2 += rw[64 + u * 3 + 2] * w1;
            }
            out[row * 256 + v]              = s  * 0.125f + sb0[v];
            out[row * 256 + 64 + v * 3 + 0] = a0 * 0.125f;
            out[row * 256 + 64 + v * 3 + 1] = a1 * 0.125f;
            out[row * 256 + 64 + v * 3 + 2] = a2 * 0.125f;
        }
        __syncthreads();
    }
}

// ---------------- gate: xg = [g_s | xv * g_v] ---------------------------------
__global__ __launch_bounds__(256) void k_gate(
    const float* __restrict__ x, float* __restrict__ xg,
    const float* __restrict__ Wg1, const float* __restrict__ bg1,
    const float* __restrict__ Wg2, const float* __restrict__ bg2,
    int nrows)
{
    __shared__ float sW1[128 * 128];
    __shared__ float sW2[128 * 128];
    __shared__ float sb1[128], sb2[128];
    __shared__ float srow[2][256];
    __shared__ float sf0[2][128];
    __shared__ float sh1[2][128];
    const int tid = threadIdx.x;
    for (int i = tid; i < 128 * 32; i += 256) {
        ((float4*)sW1)[i] = ((const float4*)Wg1)[i];
        ((float4*)sW2)[i] = ((const float4*)Wg2)[i];
    }
    if (tid < 128) { sb1[tid] = bg1[tid]; sb2[tid] = bg2[tid]; }
    __syncthreads();

    const int rr = tid >> 7;
    const int j  = tid & 127;
    for (int base = blockIdx.x * 2; base < nrows; base += gridDim.x * 2) {
        if (tid < 128) {
            int r = tid >> 6, c = tid & 63;
            int row = base + r;
            float4 v = make_float4(0.f, 0.f, 0.f, 0.f);
            if (row < nrows) v = ((const float4*)(x + (size_t)row * 256))[c];
            ((float4*)srow[r])[c] = v;
        }
        __syncthreads();
        {
            float f;
            if (j < 64) f = srow[rr][j];
            else {
                int u = j - 64;
                float v0 = srow[rr][64 + u * 3 + 0];
                float v1 = srow[rr][64 + u * 3 + 1];
                float v2 = srow[rr][64 + u * 3 + 2];
                f = sqrtf(v0 * v0 + v1 * v1 + v2 * v2 + 1e-12f);
            }
            sf0[rr][j] = f;
        }
        __syncthreads();
        {
            float acc = sb1[j];
            #pragma unroll 16
            for (int k = 0; k < 128; ++k) acc += sf0[rr][k] * sW1[k * 128 + j];
            sh1[rr][j] = acc / (1.f + expf(-acc));
        }
        __syncthreads();
        {
            float acc = sb2[j];
            #pragma unroll 16
            for (int k = 0; k < 128; ++k) acc += sh1[rr][k] * sW2[k * 128 + j];
            int row = base + rr;
            if (row < nrows) {
                if (j < 64) xg[row * 256 + j] = acc;
                else {
                    int u = j - 64;
                    xg[row * 256 + 64 + u * 3 + 0] = srow[rr][64 + u * 3 + 0] * acc;
                    xg[row * 256 + 64 + u * 3 + 1] = srow[rr][64 + u * 3 + 1] * acc;
                    xg[row * 256 + 64 + u * 3 + 2] = srow[rr][64 + u * 3 + 2] * acc;
                }
            }
        }
        __syncthreads();
    }
}

// ---------------- CSR build: counting sort of edges by dst -------------------
__global__ __launch_bounds__(256) void k_hist(const int* __restrict__ ei, int* __restrict__ hist) {
    int e = blockIdx.x * 256 + threadIdx.x;
    if (e < NEDGE) atomicAdd(&hist[ei[e]], 1);
}

// one block, 1024 threads; 20 bins per thread + Hillis-Steele over partials
__global__ __launch_bounds__(1024) void k_scan(const int* __restrict__ hist,
                                               int* __restrict__ offs,
                                               int* __restrict__ curs) {
    __shared__ int part[1024];
    const int t = threadIdx.x;
    const int base = t * 20;
    int loc[20];
    int s = 0;
    #pragma unroll
    for (int k = 0; k < 20; ++k) {
        int b = base + k;
        int v = (b < NNODE) ? hist[b] : 0;
        loc[k] = s; s += v;
    }
    part[t] = s;
    __syncthreads();
    for (int off = 1; off < 1024; off <<= 1) {
        int v = (t >= off) ? part[t - off] : 0;
        __syncthreads();
        part[t] += v;
        __syncthreads();
    }
    int excl = (t == 0) ? 0 : part[t - 1];
    #pragma unroll
    for (int k = 0; k < 20; ++k) {
        int b = base + k;
        if (b < NNODE) { offs[b] = excl + loc[k]; curs[b] = excl + loc[k]; }
    }
    if (t == 1023) offs[NNODE] = part[1023];
}

__global__ __launch_bounds__(256) void k_scatteridx(const int* __restrict__ ei,
                                                    int* __restrict__ curs,
                                                    int* __restrict__ order) {
    int e = blockIdx.x * 256 + threadIdx.x;
    if (e < NEDGE) {
        int p = atomicAdd(&curs[ei[e]], 1);
        order[p] = e;
    }
}

// ---------------- fused edge kernel (CSR, no atomics) ------------------------
// wave-per-node: walk the node's edge segment (EPW=2 batches), accumulate the
// message in registers, ONE plain store per node. dst-row gather hoisted.
// MLP micro-structure identical to R5 (per-wave LDS staging, broadcast reads).
#define EPW 2
__global__ __launch_bounds__(1024, 4) void k_edge(
    const float* __restrict__ pre, const float* __restrict__ slf,
    const int* __restrict__ ei, const float* __restrict__ eshp,
    const float* __restrict__ ea,
    const int* __restrict__ offs, const int* __restrict__ order,
    const float* __restrict__ Wf1, const float* __restrict__ Wf2,
    const float* __restrict__ Wl1, const float* __restrict__ Wl2,
    float* __restrict__ acc)
{
    __shared__ float2 sW1mb[64 * 64];     // 32KB  {wm, wb}
    __shared__ float4 sW2a[32 * 64];      // 32KB  wfa[0..3]
    __shared__ float4 sW2b[32 * 64];      // 32KB  wlb[0..3]
    __shared__ float2 sW2c[32 * 64];      // 16KB  {wfa[4], wlb[4]}
    __shared__ float  sIN[16][EPW][192];  // 24KB  per-wave input staging
    __shared__ float  sH [16][EPW][64];   // 8KB   per-wave h staging
    const int tid = threadIdx.x;
    const float sc_f1 = 0.125f;                 // 1/sqrt(64)
    const float sc_l1 = 0.07216878364870323f;   // 1/sqrt(192)
    const float sc_2  = 0.17677669529663687f;   // 1/sqrt(32)
    for (int i = tid; i < 64 * 64; i += 1024) {
        int u = i >> 6, c = i & 63, j = c & 31;
        float wm, wb;
        if (c < 32) {
            wm = Wf1[u * 32 + j] * sc_f1;
            wb = 0.f;
        } else {
            wm = (Wl1[u * 32 + j] + Wl1[(64 + u) * 32 + j]) * sc_l1;
            wb = Wl1[(128 + u) * 32 + j] * sc_l1;
        }
        sW1mb[i] = make_float2(wm, wb);
    }
    for (int i = tid; i < 32 * 64; i += 1024) {
        int jj = i >> 6, col = i & 63;
        const float* f2 = Wf2 + jj * 320 + col;
        const float* l2 = Wl2 + jj * 320 + col;
        sW2a[i] = make_float4(f2[0] * sc_2, f2[64] * sc_2, f2[128] * sc_2, f2[192] * sc_2);
        sW2b[i] = make_float4(l2[0] * sc_2, l2[64] * sc_2, l2[128] * sc_2, l2[192] * sc_2);
        sW2c[i] = make_float2(f2[256] * sc_2, l2[256] * sc_2);
    }
    __syncthreads();

    const int lane  = tid & 63;
    const int w     = tid >> 6;
    const int gwave = blockIdx.x * (blockDim.x >> 6) + w;
    const int nwav  = gridDim.x * (blockDim.x >> 6);
    const float* inb = &sIN[w][0][(lane >> 5) << 6];

    const float PW_S = 0.4472135954999579f;   // sqrt(1/5)
    const float PW_V = 0.7745966692414834f;   // sqrt(3/5)
    const float IS3  = 0.5773502691896258f;   // 1/sqrt(3)
    const float IS2  = 0.7071067811865476f;   // 1/sqrt(2)

    for (int d = gwave; d < NNODE; d += nwav) {
        const int e0 = __builtin_amdgcn_readfirstlane(offs[d]);
        const int e1 = __builtin_amdgcn_readfirstlane(offs[d + 1]);
        // hoisted dst-row gather
        float psd = pre[d * 256 + lane];
        float pd0 = pre[d * 256 + 64 + lane * 3 + 0];
        float pd1 = pre[d * 256 + 64 + lane * 3 + 1];
        float pd2 = pre[d * 256 + 64 + lane * 3 + 2];
        sIN[w][0][64 + lane] = psd;
        sIN[w][1][64 + lane] = psd;

        float accS = 0.f, aV0 = 0.f, aV1 = 0.f, aV2 = 0.f;

        for (int i = e0; i < e1; i += EPW) {
            const int cnt = e1 - i;          // >= 1, wave-uniform
            int eo[EPW], srcv[EPW];
            #pragma unroll
            for (int t = 0; t < EPW; ++t) {
                int idx = (t < cnt) ? (i + t) : i;   // clamp: duplicate edge, skipped later
                int e = __builtin_amdgcn_readfirstlane(order[idx]);
                int s = __builtin_amdgcn_readfirstlane(ei[NEDGE + e]);
                eo[t] = e; srcv[t] = s;
                float ps0 = pre[s * 256 + 64 + lane * 3 + 0];
                float ps1 = pre[s * 256 + 64 + lane * 3 + 1];
                float ps2 = pre[s * 256 + 64 + lane * 3 + 2];
                float ip1 = (pd0 * ps0 + pd1 * ps1 + pd2 * ps2) * (1.f / 3.f);
                float eav = ea[e * 64 + lane];
                sIN[w][t][lane]       = eav;
                sIN[w][t][128 + lane] = ip1;
            }
            // no barrier: same wave wrote, same wave reads (lgkmcnt ordering)

            // h-phase: lane j<32 -> hA_j (edge_attr net), lane 32+j -> hB_j (s0 net)
            float hacc[EPW] = {0.f, 0.f};
            #pragma unroll 16
            for (int uu = 0; uu < 64; ++uu) {
                float2 wmb = sW1mb[uu * 64 + lane];
                #pragma unroll
                for (int t = 0; t < EPW; ++t) {
                    float b1 = inb[t * 192 + uu];          // eav (lo) / psd (hi)
                    float bI = sIN[w][t][128 + uu];        // ip1 broadcast
                    hacc[t] += b1 * wmb.x + bI * wmb.y;
                }
            }
            #pragma unroll
            for (int t = 0; t < EPW; ++t) sH[w][t][lane] = sspf(hacc[t]);

            // combine: aA[k] = hA . Wf2[:,k*64+lane], aB[k] = hB . Wl2[:,k*64+lane]
            float aA[EPW][5], aB[EPW][5];
            #pragma unroll
            for (int t = 0; t < EPW; ++t)
                #pragma unroll
                for (int k = 0; k < 5; ++k) { aA[t][k] = 0.f; aB[t][k] = 0.f; }
            #pragma unroll 8
            for (int jj = 0; jj < 32; ++jj) {
                float4 wa = sW2a[jj * 64 + lane];
                float4 wb = sW2b[jj * 64 + lane];
                float2 wc = sW2c[jj * 64 + lane];
                #pragma unroll
                for (int t = 0; t < EPW; ++t) {
                    float hA = sH[w][t][jj];
                    float hB = sH[w][t][32 + jj];
                    aA[t][0] += hA * wa.x; aA[t][1] += hA * wa.y;
                    aA[t][2] += hA * wa.z; aA[t][3] += hA * wa.w;
                    aA[t][4] += hA * wc.x;
                    aB[t][0] += hB * wb.x; aB[t][1] += hB * wb.y;
                    aB[t][2] += hB * wb.z; aB[t][3] += hB * wb.w;
                    aB[t][4] += hB * wc.y;
                }
            }

            // tensor product + register accumulation (skip clamped duplicate)
            #pragma unroll
            for (int t = 0; t < EPW; ++t) {
                if (t >= cnt) break;          // wave-uniform
                int e = eo[t], s = srcv[t];
                float w0 = aA[t][0] * aB[t][0];
                float w1 = aA[t][1] * aB[t][1];
                float w2 = aA[t][2] * aB[t][2];
                float w3 = aA[t][3] * aB[t][3];
                float w4 = aA[t][4] * aB[t][4];
                float es  = slf[s * 256 + lane];
                float ev0 = slf[s * 256 + 64 + lane * 3 + 0];
                float ev1 = slf[s * 256 + 64 + lane * 3 + 1];
                float ev2 = slf[s * 256 + 64 + lane * 3 + 2];
                float s0v = eshp[e * 4 + 0];
                float sx  = eshp[e * 4 + 1];
                float sy  = eshp[e * 4 + 2];
                float sz  = eshp[e * 4 + 3];
                float dotv = ev0 * sx + ev1 * sy + ev2 * sz;
                accS += PW_S * (w0 * es * s0v + w3 * dotv * IS3);
                float cx = ev1 * sz - ev2 * sy;
                float cy = ev2 * sx - ev0 * sz;
                float cz = ev0 * sy - ev1 * sx;
                aV0 += PW_V * (w1 * es * sx + w2 * ev0 * s0v + w4 * cx * IS2);
                aV1 += PW_V * (w1 * es * sy + w2 * ev1 * s0v + w4 * cy * IS2);
                aV2 += PW_V * (w1 * es * sz + w2 * ev2 * s0v + w4 * cz * IS2);
            }
        }

        // one plain coalesced store per node
        acc[d * 256 + lane]              = accS;
        acc[d * 256 + 64 + lane * 3 + 0] = aV0;
        acc[d * 256 + 64 + lane * 3 + 1] = aV1;
        acc[d * 256 + 64 + lane * 3 + 2] = aV2;
    }
}

extern "C" void kernel_launch(void* const* d_in, const int* in_sizes, int n_in,
                              void* d_out, int out_size, void* d_ws, size_t ws_size,
                              hipStream_t stream) {
    const float* x     = (const float*)d_in[0];
    const int*   ei    = (const int*)  d_in[1];
    const float* esh   = (const float*)d_in[2];
    const float* eattr = (const float*)d_in[3];
    const float* Wpre0 = (const float*)d_in[4];
    const float* bpre0 = (const float*)d_in[5];
    const float* Wpre1 = (const float*)d_in[6];
    const float* Wg1   = (const float*)d_in[7];
    const float* bg1   = (const float*)d_in[8];
    const float* Wg2   = (const float*)d_in[9];
    const float* bg2   = (const float*)d_in[10];
    const float* Wn0   = (const float*)d_in[11];
    const float* bn0   = (const float*)d_in[12];
    const float* Wn1   = (const float*)d_in[13];
    const float* Wf1   = (const float*)d_in[14];
    const float* Wf2   = (const float*)d_in[15];
    const float* Wl1   = (const float*)d_in[16];
    const float* Wl2   = (const float*)d_in[17];
    const float* Wo0   = (const float*)d_in[18];
    const float* bo0   = (const float*)d_in[19];
    const float* Wo1   = (const float*)d_in[20];
    float* out = (float*)d_out;
    float* ws  = (float*)d_ws;

    float* pre = ws;                               // N*256 f
    float* xg  = ws + (size_t)NNODE * 256;         // N*256 f
    float* slf = ws + (size_t)NNODE * 256 * 2;     // N*256 f
    float* acc = ws + (size_t)NNODE * 256 * 3;     // N*256 f
    int*   hist  = (int*)(ws + (size_t)NNODE * 256 * 4);  // 20000
    int*   offs  = hist + NNODE;                          // 20001
    int*   curs  = offs + NNODE + 2;                      // 20000
    int*   order = curs + NNODE;                          // 320000

    hipMemsetAsync(hist, 0, NNODE * sizeof(int), stream);
    k_hist      <<<(NEDGE + 255) / 256, 256, 0, stream>>>(ei, hist);
    k_scan      <<<1, 1024, 0, stream>>>(hist, offs, curs);
    k_scatteridx<<<(NEDGE + 255) / 256, 256, 0, stream>>>(ei, curs, order);

    k_e3lin<<<1280, 256, 0, stream>>>(x,  nullptr, pre, Wpre0, bpre0, Wpre1, NNODE);
    k_gate <<<512,  256, 0, stream>>>(x,  xg, Wg1, bg1, Wg2, bg2, NNODE);
    k_e3lin<<<1280, 256, 0, stream>>>(xg, nullptr, slf, Wn0, bn0, Wn1, NNODE);
    k_edge <<<256, 1024, 0, stream>>>(pre, slf, ei, esh, eattr, offs, order,
                                      Wf1, Wf2, Wl1, Wl2, acc);
    k_e3lin<<<1280, 256, 0, stream>>>(acc, slf, out, Wo0, bo0, Wo1, NNODE);
}